// Round 8
// baseline (38.652 us; speedup 1.0000x reference)
//
#include <hip/hip_runtime.h>
#include <math.h>

// Every rounding is deliberate: bit-match the reference fp32 pipeline
// (ascending single-accumulator FMA dot — verified rounds 4-7, absmax=0).
#pragma clang fp contract(off)

constexpr int KCODES = 2048;   // EMBEDDING_LENGTH
constexpr int CDIM   = 4;      // EMBEDDING_DIM
constexpr int KSPLIT = 8;      // one k-chunk per wave
constexpr int KCHUNK = KCODES / KSPLIT;  // 256 codes per wave
constexpr int ROWS   = 64;     // rows per block (= lanes per wave)

// Single fused kernel.
//  - 512 threads = 8 waves; wave w owns k-chunk w for the block's 64 rows.
//  - Embedding table staged in LDS; inner-loop reads are WAVE-UNIFORM
//    ds_read broadcasts: conflict-free, immediate-offset addressed, and DS
//    returns IN-ORDER so the compiler can use fine-grained lgkmcnt(N)
//    (unlike s_load, which forces lgkmcnt(0) drains -- round 7's residual).
//  - LDS exactly 40 KB (skey reduce reuses sE after a barrier)
//    -> 4 blocks/CU; __launch_bounds__(512,8) pins VGPRs <= 64 for 100% occ.
__global__ __launch_bounds__(512, 8) void vq_fused(
    const float* __restrict__ x,
    const float* __restrict__ emb,
    int* __restrict__ out,
    int N)
{
    __shared__ float4 sE[KCODES];   // 32 KB; reused for skey after main loop
    __shared__ float  sE2[KCODES];  //  8 KB

    const int t = threadIdx.x;

    // Stage table: 4 codes per thread, coalesced float4 loads.
    for (int i = t; i < KCODES; i += 512) {
        float4 e = reinterpret_cast<const float4*>(emb)[i];
        sE[i] = e;
        // e2 = np.sum(emb*emb, -1): ascending unfused mul-add (n<8 scalar loop)
        sE2[i] = ((e.x * e.x + e.y * e.y) + e.z * e.z) + e.w * e.w;
    }
    __syncthreads();

    const int lane = t & 63;        // row within block
    const int n    = blockIdx.x * ROWS + lane;
    // wave id == k-chunk id; force uniform -> SGPR (round-6 lesson: t>>6 is
    // not provably uniform to divergence analysis; losing this costs 2x).
    const int wid   = __builtin_amdgcn_readfirstlane(t >> 6);
    const int kbase = wid * KCHUNK;

    unsigned long long key = ~0ull;
    if (n < N) {
        const float4 xv = reinterpret_cast<const float4*>(x)[n];
        const float x2 = ((xv.x * xv.x + xv.y * xv.y) + xv.z * xv.z) + xv.w * xv.w;

        // 4 independent (min, idx) chains for ILP; indices ≡ u (mod 4).
        float dmin[4] = {HUGE_VALF, HUGE_VALF, HUGE_VALF, HUGE_VALF};
        int   bi[4]   = {0, 0, 0, 0};

        #pragma unroll 4
        for (int i = 0; i < KCHUNK / 4; ++i) {
            #pragma unroll
            for (int u = 0; u < 4; ++u) {
                // uniform-address LDS broadcast; offset folds to immediate
                const float4 e = sE[kbase + i * 4 + u];
                const float  s = sE2[kbase + i * 4 + u];
                // ascending FMA chain (the verified reference pipeline)
                float dot = xv.x * e.x;
                dot = __builtin_fmaf(xv.y, e.y, dot);
                dot = __builtin_fmaf(xv.z, e.z, dot);
                dot = __builtin_fmaf(xv.w, e.w, dot);
                float tmp = __builtin_fmaf(-2.0f, dot, x2);  // == x2 - 2*dot
                float d = tmp + s;
                if (d < dmin[u]) { dmin[u] = d; bi[u] = i; } // strict <: first occ.
            }
        }

        // Merge chains; smaller global index wins exact ties (np.argmin).
        float bm = dmin[0];
        int   bidx = kbase + (bi[0] << 2) + 0;
        #pragma unroll
        for (int u = 1; u < 4; ++u) {
            int idx_u = kbase + (bi[u] << 2) + u;
            if (dmin[u] < bm || (dmin[u] == bm && idx_u < bidx)) {
                bm = dmin[u]; bidx = idx_u;
            }
        }

        // d >= 0 for this data, so float bits are order-isomorphic as u32;
        // low bits break exact ties toward the smaller index.
        key = ((unsigned long long)__float_as_uint(bm) << 32) | (unsigned)bidx;
    }

    // Cross-wave reduce: reuse sE's LDS (all waves are done reading it).
    __syncthreads();
    unsigned long long* skey = reinterpret_cast<unsigned long long*>(sE);
    skey[lane * (KSPLIT + 1) + wid] = key;   // +1 stride: no bank conflict
    __syncthreads();

    if (t < ROWS) {
        const int rn = blockIdx.x * ROWS + t;
        if (rn < N) {
            unsigned long long k = skey[t * (KSPLIT + 1)];
            #pragma unroll
            for (int s = 1; s < KSPLIT; ++s) {
                unsigned long long v = skey[t * (KSPLIT + 1) + s];
                if (v < k) k = v;
            }
            out[rn] = (int)(unsigned)(k & 0xFFFFFFFFull);
        }
    }
}

extern "C" void kernel_launch(void* const* d_in, const int* in_sizes, int n_in,
                              void* d_out, int out_size, void* d_ws, size_t ws_size,
                              hipStream_t stream) {
    const float* x   = (const float*)d_in[0];   // [16,64,64,4] -> [N,4]
    const float* emb = (const float*)d_in[1];   // [2048,4]
    int* out = (int*)d_out;                     // [N] int32
    const int N = in_sizes[0] / CDIM;           // 65536

    vq_fused<<<(N + ROWS - 1) / ROWS, 512, 0, stream>>>(x, emb, out, N);
}

// Round 9
// 30.595 us; speedup vs baseline: 1.2634x; 1.2634x over previous
//
#include <hip/hip_runtime.h>
#include <math.h>

// Every rounding is deliberate: bit-match the reference fp32 pipeline
// (ascending single-accumulator FMA dot — verified rounds 4-8, absmax=0).
#pragma clang fp contract(off)

typedef __attribute__((ext_vector_type(2))) float f2;

constexpr int KCODES = 2048;   // EMBEDDING_LENGTH
constexpr int CDIM   = 4;      // EMBEDDING_DIM
constexpr int KSPLIT = 8;      // one k-chunk per wave
constexpr int KCHUNK = KCODES / KSPLIT;  // 256 codes per wave
constexpr int ROWS   = 64;     // rows per block (= lanes per wave)
constexpr int NUNITS = KCODES / 2;       // 1024 two-code units

// Packed fp32 ops (CDNA2+). Each half is an IEEE-RNE op identical to the
// scalar v_fma_f32/v_mul_f32/v_add_f32 — so the per-code distance pipeline
// remains bitwise identical to the verified reference pipeline.
__device__ __forceinline__ f2 pk_mul(f2 a, f2 b) {
    f2 d; asm("v_pk_mul_f32 %0, %1, %2" : "=v"(d) : "v"(a), "v"(b)); return d;
}
__device__ __forceinline__ f2 pk_fma(f2 a, f2 b, f2 c) {
    f2 d; asm("v_pk_fma_f32 %0, %1, %2, %3" : "=v"(d) : "v"(a), "v"(b), "v"(c)); return d;
}
__device__ __forceinline__ f2 pk_add(f2 a, f2 b) {
    f2 d; asm("v_pk_add_f32 %0, %1, %2" : "=v"(d) : "v"(a), "v"(b)); return d;
}
__device__ __forceinline__ float min3f(float a, float b, float c) {
    float d; asm("v_min3_f32 %0, %1, %2, %3" : "=v"(d) : "v"(a), "v"(b), "v"(c)); return d;
}

__device__ __forceinline__ float sumsq(float4 e) {
    // np.sum(e*e, -1): ascending unfused mul-add (n<8 scalar loop)
    return ((e.x * e.x + e.y * e.y) + e.z * e.z) + e.w * e.w;
}

// Single fused kernel. 512 threads = 8 waves; wave w owns k-chunk w for the
// block's 64 rows. Main loop: 2 codes per packed instruction, dmin-only
// tracking (v_min3_f32 is exact), 8-code group id for deferred index
// resolution. DS traffic: 10x uniform ds_read_b128 per 8 codes (1.25/code,
// down from 2/code in round 8 — the DS pipe was the bottleneck).
__global__ __launch_bounds__(512, 4) void vq_fused(
    const float* __restrict__ x,
    const float* __restrict__ emb,
    int* __restrict__ out,
    int N)
{
    __shared__ float4 sEP[NUNITS * 2];   // 32 KB: {e0a,e0b,e1a,e1b}{e2a,e2b,e3a,e3b} per unit
    __shared__ float4 sSP[KCODES / 4];   //  8 KB: s packed 4 codes per float4

    const float4* __restrict__ embf4 = reinterpret_cast<const float4*>(emb);
    const int t = threadIdx.x;

    // ---- stage transposed-pair tables (one-time; conflicts negligible) ----
    for (int j = t; j < NUNITS; j += 512) {
        float4 a = embf4[2 * j], b = embf4[2 * j + 1];
        sEP[2 * j]     = make_float4(a.x, b.x, a.y, b.y);
        sEP[2 * j + 1] = make_float4(a.z, b.z, a.w, b.w);
    }
    for (int q = t; q < KCODES / 4; q += 512) {
        float4 e0 = embf4[4 * q], e1 = embf4[4 * q + 1];
        float4 e2 = embf4[4 * q + 2], e3 = embf4[4 * q + 3];
        sSP[q] = make_float4(sumsq(e0), sumsq(e1), sumsq(e2), sumsq(e3));
    }
    __syncthreads();

    const int lane = t & 63;
    const int n    = blockIdx.x * ROWS + lane;
    // wave id == k-chunk id; force uniform -> SGPR (round-6 lesson).
    const int wid   = __builtin_amdgcn_readfirstlane(t >> 6);
    const int kbase = wid * KCHUNK;
    const int ubase = kbase >> 1;   // first unit of chunk
    const int qbase = kbase >> 2;   // first s-quad of chunk

    unsigned long long key = ~0ull;
    if (n < N) {
        const float4 xv = reinterpret_cast<const float4*>(x)[n];
        const float x2 = ((xv.x * xv.x + xv.y * xv.y) + xv.z * xv.z) + xv.w * xv.w;
        const f2 xx = {xv.x, xv.x}, yy = {xv.y, xv.y};
        const f2 zz = {xv.z, xv.z}, ww = {xv.w, xv.w};
        const f2 x2p = {x2, x2};
        const f2 m2  = {-2.0f, -2.0f};

        float dmin = HUGE_VALF;
        int bg = 0;   // winning 8-code group within the chunk

        for (int g = 0; g < KCHUNK / 8; ++g) {   // 32 groups x 8 codes
            const float prev = dmin;
            const float4 sA = sSP[qbase + 2 * g];
            const float4 sB = sSP[qbase + 2 * g + 1];
            const int u0 = ubase + 4 * g;
            #pragma unroll
            for (int uu = 0; uu < 4; ++uu) {
                const float4 qa = sEP[2 * (u0 + uu)];
                const float4 qb = sEP[2 * (u0 + uu) + 1];
                const f2 sp = (uu == 0) ? f2{sA.x, sA.y} :
                              (uu == 1) ? f2{sA.z, sA.w} :
                              (uu == 2) ? f2{sB.x, sB.y} : f2{sB.z, sB.w};
                // ascending FMA chain, two codes at once (halves independent)
                f2 dot = pk_mul(xx, f2{qa.x, qa.y});
                dot = pk_fma(yy, f2{qa.z, qa.w}, dot);
                dot = pk_fma(zz, f2{qb.x, qb.y}, dot);
                dot = pk_fma(ww, f2{qb.z, qb.w}, dot);
                f2 dd = pk_add(pk_fma(m2, dot, x2p), sp);  // (x2-2dot)+s
                dmin = min3f(dmin, dd.x, dd.y);            // exact min
            }
            if (dmin < prev) bg = g;   // strict <: earliest group keeps ties
        }

        // ---- index resolution: recompute the 8 winning codes with the
        // scalar pipeline (bitwise == packed halves), ascending, first match.
        const int k0 = kbase + (bg << 3);
        int idx = 0x7fffffff;
        #pragma unroll
        for (int r = 0; r < 8; ++r) {
            const int k = k0 + r;
            const float4 e = embf4[k];          // global, L2-hot (32 KB table)
            const float s = sumsq(e);
            float dot = xv.x * e.x;
            dot = __builtin_fmaf(xv.y, e.y, dot);
            dot = __builtin_fmaf(xv.z, e.z, dot);
            dot = __builtin_fmaf(xv.w, e.w, dot);
            const float d = __builtin_fmaf(-2.0f, dot, x2) + s;
            idx = min(idx, (d == dmin) ? k : 0x7fffffff);
        }

        // d >= 0 for this data: float bits order-isomorphic as u32; low bits
        // break exact ties toward the smaller index.
        key = ((unsigned long long)__float_as_uint(dmin) << 32) | (unsigned)idx;
    }

    // ---- cross-wave reduce: reuse sEP's LDS after a barrier ----
    __syncthreads();
    unsigned long long* skey = reinterpret_cast<unsigned long long*>(sEP);
    skey[lane * (KSPLIT + 1) + wid] = key;   // +1 stride: no bank conflict
    __syncthreads();

    if (t < ROWS) {
        const int rn = blockIdx.x * ROWS + t;
        if (rn < N) {
            unsigned long long k = skey[t * (KSPLIT + 1)];
            #pragma unroll
            for (int s = 1; s < KSPLIT; ++s) {
                unsigned long long v = skey[t * (KSPLIT + 1) + s];
                if (v < k) k = v;
            }
            out[rn] = (int)(unsigned)(k & 0xFFFFFFFFull);
        }
    }
}

extern "C" void kernel_launch(void* const* d_in, const int* in_sizes, int n_in,
                              void* d_out, int out_size, void* d_ws, size_t ws_size,
                              hipStream_t stream) {
    const float* x   = (const float*)d_in[0];   // [16,64,64,4] -> [N,4]
    const float* emb = (const float*)d_in[1];   // [2048,4]
    int* out = (int*)d_out;                     // [N] int32
    const int N = in_sizes[0] / CDIM;           // 65536

    vq_fused<<<(N + ROWS - 1) / ROWS, 512, 0, stream>>>(x, emb, out, N);
}

// Round 10
// 30.205 us; speedup vs baseline: 1.2797x; 1.0129x over previous
//
#include <hip/hip_runtime.h>
#include <math.h>

// Every rounding is deliberate: bit-match the reference fp32 pipeline
// (ascending single-accumulator FMA dot — verified rounds 4-9, absmax=0).
#pragma clang fp contract(off)

typedef __attribute__((ext_vector_type(2))) float f2;

constexpr int KCODES = 2048;   // EMBEDDING_LENGTH
constexpr int CDIM   = 4;      // EMBEDDING_DIM
constexpr int KSPLIT = 8;      // one k-chunk per wave
constexpr int KCHUNK = KCODES / KSPLIT;  // 256 codes per wave
constexpr int RPT    = 4;      // rows per lane  (DS amortization: /4 traffic)
constexpr int ROWSPB = 64 * RPT;         // 256 rows per block
constexpr int NUNITS = KCODES / 2;       // 1024 two-code units

// Packed fp32 ops (VOP3P). Each half is an IEEE-RNE op identical to scalar
// v_fma/v_mul/v_add — per-code distance pipeline stays bitwise identical to
// the verified reference pipeline (HW-confirmed round 9, absmax=0).
__device__ __forceinline__ f2 pk_mul(f2 a, f2 b) {
    f2 d; asm("v_pk_mul_f32 %0, %1, %2" : "=v"(d) : "v"(a), "v"(b)); return d;
}
__device__ __forceinline__ f2 pk_fma(f2 a, f2 b, f2 c) {
    f2 d; asm("v_pk_fma_f32 %0, %1, %2, %3" : "=v"(d) : "v"(a), "v"(b), "v"(c)); return d;
}
__device__ __forceinline__ f2 pk_add(f2 a, f2 b) {
    f2 d; asm("v_pk_add_f32 %0, %1, %2" : "=v"(d) : "v"(a), "v"(b)); return d;
}
__device__ __forceinline__ float min3f(float a, float b, float c) {
    float d; asm("v_min3_f32 %0, %1, %2, %3" : "=v"(d) : "v"(a), "v"(b), "v"(c)); return d;
}

__device__ __forceinline__ float sumsq(float4 e) {
    // np.sum(e*e, -1): ascending unfused mul-add (n<8 scalar loop)
    return ((e.x * e.x + e.y * e.y) + e.z * e.z) + e.w * e.w;
}

// 512 threads = 8 waves; wave w owns k-chunk w for the block's 256 rows
// (4 rows/lane). DS traffic per CU: 8 waves x 320 uniform ds_read_b128
// ~ 15K cyc ~ 6.4 us, matched to the packed-VALU floor (~6 us).
__global__ __launch_bounds__(512) void vq_fused(
    const float* __restrict__ x,
    const float* __restrict__ emb,
    int* __restrict__ out,
    int N)
{
    __shared__ float4 sEP[NUNITS * 2];   // 32 KB: {e0a,e0b,e1a,e1b}{e2a,e2b,e3a,e3b}
    __shared__ float4 sSP[KCODES / 4];   //  8 KB: s packed 4/quad

    const float4* __restrict__ embf4 = reinterpret_cast<const float4*>(emb);
    const int t = threadIdx.x;

    for (int j = t; j < NUNITS; j += 512) {
        float4 a = embf4[2 * j], b = embf4[2 * j + 1];
        sEP[2 * j]     = make_float4(a.x, b.x, a.y, b.y);
        sEP[2 * j + 1] = make_float4(a.z, b.z, a.w, b.w);
    }
    for (int q = t; q < KCODES / 4; q += 512) {
        float4 e0 = embf4[4 * q],     e1 = embf4[4 * q + 1];
        float4 e2 = embf4[4 * q + 2], e3 = embf4[4 * q + 3];
        sSP[q] = make_float4(sumsq(e0), sumsq(e1), sumsq(e2), sumsq(e3));
    }
    __syncthreads();

    const int lane = t & 63;
    // wave id == k-chunk id; force uniform -> SGPR (round-6 lesson: costs 2x).
    const int wid   = __builtin_amdgcn_readfirstlane(t >> 6);
    const int kbase = wid * KCHUNK;
    const int ubase = kbase >> 1;
    const int qbase = kbase >> 2;
    const int nbase = blockIdx.x * ROWSPB + lane;

    float4 xv[RPT];
    f2 xx[RPT], yy[RPT], zz[RPT], ww[RPT], x2p[RPT];
    float dmin[RPT];
    int   bg[RPT];
    #pragma unroll
    for (int r = 0; r < RPT; ++r) {
        const int n = nbase + r * 64;
        xv[r] = (n < N) ? reinterpret_cast<const float4*>(x)[n]
                        : make_float4(0.f, 0.f, 0.f, 0.f);
        const float x2 = ((xv[r].x * xv[r].x + xv[r].y * xv[r].y)
                          + xv[r].z * xv[r].z) + xv[r].w * xv[r].w;
        xx[r] = f2{xv[r].x, xv[r].x}; yy[r] = f2{xv[r].y, xv[r].y};
        zz[r] = f2{xv[r].z, xv[r].z}; ww[r] = f2{xv[r].w, xv[r].w};
        x2p[r] = f2{x2, x2};
        dmin[r] = HUGE_VALF; bg[r] = 0;
    }
    const f2 m2 = {-2.0f, -2.0f};

    for (int g = 0; g < KCHUNK / 8; ++g) {   // 32 groups x 8 codes
        float prev[RPT];
        #pragma unroll
        for (int r = 0; r < RPT; ++r) prev[r] = dmin[r];

        const float4 sA = sSP[qbase + 2 * g];
        const float4 sB = sSP[qbase + 2 * g + 1];
        const int u0 = ubase + 4 * g;
        #pragma unroll
        for (int uu = 0; uu < 4; ++uu) {
            const float4 qa = sEP[2 * (u0 + uu)];
            const float4 qb = sEP[2 * (u0 + uu) + 1];
            const f2 ea = {qa.x, qa.y}, eb = {qa.z, qa.w};
            const f2 ec = {qb.x, qb.y}, ed = {qb.z, qb.w};
            const f2 sp = (uu == 0) ? f2{sA.x, sA.y} :
                          (uu == 1) ? f2{sA.z, sA.w} :
                          (uu == 2) ? f2{sB.x, sB.y} : f2{sB.z, sB.w};
            #pragma unroll
            for (int r = 0; r < RPT; ++r) {
                // ascending FMA chain, two codes at once (halves independent)
                f2 dot = pk_mul(xx[r], ea);
                dot = pk_fma(yy[r], eb, dot);
                dot = pk_fma(zz[r], ec, dot);
                dot = pk_fma(ww[r], ed, dot);
                f2 dd = pk_add(pk_fma(m2, dot, x2p[r]), sp);  // (x2-2dot)+s
                dmin[r] = min3f(dmin[r], dd.x, dd.y);         // exact min
            }
        }
        #pragma unroll
        for (int r = 0; r < RPT; ++r)
            if (dmin[r] < prev[r]) bg[r] = g;   // strict <: earliest group ties
    }

    // ---- index resolution: recompute the 8 winning codes per row with the
    // scalar pipeline (bitwise == packed halves), ascending, first match.
    // Reads go to global (L2-hot 32 KB table) to keep the DS pipe clean.
    unsigned long long key[RPT];
    #pragma unroll
    for (int r = 0; r < RPT; ++r) {
        const int k0 = kbase + (bg[r] << 3);
        int idx = 0x7fffffff;
        #pragma unroll
        for (int q = 0; q < 8; ++q) {
            const int k = k0 + q;
            const float4 e = embf4[k];
            const float s = sumsq(e);
            float dot = xv[r].x * e.x;
            dot = __builtin_fmaf(xv[r].y, e.y, dot);
            dot = __builtin_fmaf(xv[r].z, e.z, dot);
            dot = __builtin_fmaf(xv[r].w, e.w, dot);
            const float d = __builtin_fmaf(-2.0f, dot, x2p[r].x) + s;
            idx = min(idx, (d == dmin[r]) ? k : 0x7fffffff);
        }
        // d >= 0 here: float bits order-isomorphic as u32; low bits break
        // exact ties toward the smaller index.
        key[r] = ((unsigned long long)__float_as_uint(dmin[r]) << 32) | (unsigned)idx;
    }

    // ---- cross-wave reduce: reuse sEP's LDS (9-u64 stride: 2-way = free) ----
    __syncthreads();
    unsigned long long* skey = reinterpret_cast<unsigned long long*>(sEP);
    #pragma unroll
    for (int r = 0; r < RPT; ++r)
        skey[(r * 64 + lane) * (KSPLIT + 1) + wid] = key[r];
    __syncthreads();

    if (t < ROWSPB) {
        const int rn = blockIdx.x * ROWSPB + t;
        if (rn < N) {
            unsigned long long k = skey[t * (KSPLIT + 1)];
            #pragma unroll
            for (int s = 1; s < KSPLIT; ++s) {
                unsigned long long v = skey[t * (KSPLIT + 1) + s];
                if (v < k) k = v;
            }
            out[rn] = (int)(unsigned)(k & 0xFFFFFFFFull);
        }
    }
}

extern "C" void kernel_launch(void* const* d_in, const int* in_sizes, int n_in,
                              void* d_out, int out_size, void* d_ws, size_t ws_size,
                              hipStream_t stream) {
    const float* x   = (const float*)d_in[0];   // [16,64,64,4] -> [N,4]
    const float* emb = (const float*)d_in[1];   // [2048,4]
    int* out = (int*)d_out;                     // [N] int32
    const int N = in_sizes[0] / CDIM;           // 65536

    vq_fused<<<(N + ROWSPB - 1) / ROWSPB, 512, 0, stream>>>(x, emb, out, N);
}